// Round 1
// baseline (36490.570 us; speedup 1.0000x reference)
//
#include <hip/hip_runtime.h>
#include <math.h>

#define HID     512
#define THID    1536          // 3*HID
#define OUT_V   128
#define MAXLEN  41
#define BATCH   4096
#define BOS_IDX 2

#define FLAG_ACC  1
#define FLAG_RELU 2

// ---------------------------------------------------------------------------
// embed: out[b, :] = table[tok[b], :]   (toks == nullptr -> BOS token)
// ---------------------------------------------------------------------------
__global__ void embed_kernel(const int* __restrict__ toks,
                             const float* __restrict__ table,
                             float* __restrict__ out)
{
    int idx = blockIdx.x * blockDim.x + threadIdx.x;
    if (idx >= BATCH * HID) return;
    int b = idx / HID;
    int i = idx - b * HID;
    int tok = toks ? toks[b] : BOS_IDX;
    out[idx] = table[tok * HID + i];
}

// ---------------------------------------------------------------------------
// C[M,N] = A[M,K] * B[N,K]^T (+bias) (+=C) (relu)
// A row-major stride lda, B row-major stride ldb (we dot rows of A with rows
// of B -- all torch Linear weights are stored [out_features, in_features]).
// K must be a multiple of 16 (always 512 here).
// ---------------------------------------------------------------------------
#define BM 64
#define BN 64
#define BK 16

__global__ __launch_bounds__(256)
void gemm_nt(const float* __restrict__ A, int lda,
             const float* __restrict__ B, int ldb,
             const float* __restrict__ bias,
             float* __restrict__ C, int ldc,
             int M, int N, int K, int flags)
{
    __shared__ float As[BM][BK + 1];   // +1 pad: 16-way -> 2-way (free) conflicts
    __shared__ float Bs[BN][BK + 1];

    const int tid = threadIdx.x;       // 0..255
    const int tx  = tid & 15;
    const int ty  = tid >> 4;
    const int bm  = blockIdx.y * BM;
    const int bn  = blockIdx.x * BN;
    const int lr  = tid >> 2;          // 0..63  tile row to load
    const int lc  = (tid & 3) << 2;    // 0,4,8,12 k-offset to load (float4)

    float acc[4][4] = {{0.f, 0.f, 0.f, 0.f}, {0.f, 0.f, 0.f, 0.f},
                       {0.f, 0.f, 0.f, 0.f}, {0.f, 0.f, 0.f, 0.f}};

    for (int k0 = 0; k0 < K; k0 += BK) {
        float4 av = make_float4(0.f, 0.f, 0.f, 0.f);
        float4 bv = make_float4(0.f, 0.f, 0.f, 0.f);
        int ar = bm + lr;
        if (ar < M) av = *(const float4*)(A + (size_t)ar * lda + k0 + lc);
        int br = bn + lr;
        if (br < N) bv = *(const float4*)(B + (size_t)br * ldb + k0 + lc);
        As[lr][lc + 0] = av.x; As[lr][lc + 1] = av.y;
        As[lr][lc + 2] = av.z; As[lr][lc + 3] = av.w;
        Bs[lr][lc + 0] = bv.x; Bs[lr][lc + 1] = bv.y;
        Bs[lr][lc + 2] = bv.z; Bs[lr][lc + 3] = bv.w;
        __syncthreads();

        #pragma unroll
        for (int kk = 0; kk < BK; ++kk) {
            float a[4], b[4];
            #pragma unroll
            for (int i = 0; i < 4; ++i) a[i] = As[ty * 4 + i][kk];
            #pragma unroll
            for (int j = 0; j < 4; ++j) b[j] = Bs[tx * 4 + j][kk];
            #pragma unroll
            for (int i = 0; i < 4; ++i)
                #pragma unroll
                for (int j = 0; j < 4; ++j)
                    acc[i][j] = fmaf(a[i], b[j], acc[i][j]);
        }
        __syncthreads();
    }

    #pragma unroll
    for (int i = 0; i < 4; ++i) {
        int r = bm + ty * 4 + i;
        if (r >= M) continue;
        #pragma unroll
        for (int j = 0; j < 4; ++j) {
            int c = bn + tx * 4 + j;
            if (c >= N) continue;
            float v = acc[i][j];
            if (bias) v += bias[c];
            float* p = C + (size_t)r * ldc + c;
            if (flags & FLAG_ACC)  v += *p;
            if (flags & FLAG_RELU) v = fmaxf(v, 0.f);
            *p = v;
        }
    }
}

// ---------------------------------------------------------------------------
// GRU gates (PyTorch order r,z,n):  h = (1-z)*n + z*h
// ---------------------------------------------------------------------------
__global__ void gru_gates_kernel(const float* __restrict__ gi,
                                 const float* __restrict__ gh,
                                 float* __restrict__ h)
{
    int idx = blockIdx.x * blockDim.x + threadIdx.x;
    if (idx >= BATCH * HID) return;
    int b = idx / HID;
    int i = idx - b * HID;
    const float* gib = gi + (size_t)b * THID;
    const float* ghb = gh + (size_t)b * THID;
    float ir = gib[i], iz = gib[HID + i], in = gib[2 * HID + i];
    float hr = ghb[i], hz = ghb[HID + i], hn = ghb[2 * HID + i];
    float r = 1.f / (1.f + expf(-(ir + hr)));
    float z = 1.f / (1.f + expf(-(iz + hz)));
    float n = tanhf(in + r * hn);
    float hv = h[idx];
    h[idx] = (1.f - z) * n + z * hv;
}

// enc_pad[t, :] = h[0, :]   (only batch row 0, per reference semantics)
__global__ void copy_row0_kernel(const float* __restrict__ h,
                                 float* __restrict__ dst)
{
    int i = blockIdx.x * blockDim.x + threadIdx.x;
    if (i < HID) dst[i] = h[i];
}

// softmax over MAXLEN=41 columns, one wave (64 lanes) per row
__global__ void softmax41_kernel(float* __restrict__ s)
{
    int gtid = blockIdx.x * blockDim.x + threadIdx.x;
    int row  = gtid >> 6;
    int lane = gtid & 63;
    if (row >= BATCH) return;
    float* p = s + (size_t)row * MAXLEN;
    float v = (lane < MAXLEN) ? p[lane] : -INFINITY;
    float m = v;
    #pragma unroll
    for (int o = 32; o > 0; o >>= 1) m = fmaxf(m, __shfl_xor(m, o));
    float e = (lane < MAXLEN) ? expf(v - m) : 0.f;
    float sum = e;
    #pragma unroll
    for (int o = 32; o > 0; o >>= 1) sum += __shfl_xor(sum, o);
    if (lane < MAXLEN) p[lane] = e / sum;
}

// ctx[b, i] = sum_t aw[b,t] * enc_pad[t,i]   (enc_pad is tiny -> cached)
__global__ void ctx_kernel(const float* __restrict__ aw,
                           const float* __restrict__ enc_pad,
                           float* __restrict__ ctx)
{
    int idx = blockIdx.x * blockDim.x + threadIdx.x;
    if (idx >= BATCH * HID) return;
    int b = idx / HID;
    int i = idx - b * HID;
    const float* awb = aw + (size_t)b * MAXLEN;
    float acc = 0.f;
    #pragma unroll
    for (int t = 0; t < MAXLEN; ++t)
        acc = fmaf(awb[t], enc_pad[t * HID + i], acc);
    ctx[idx] = acc;
}

// log_softmax over 128 logits + gather target + masked accumulate into scores
__global__ void out_gather_kernel(const float* __restrict__ logits,
                                  const int* __restrict__ tgt_row,
                                  float* __restrict__ scores)
{
    int gtid = blockIdx.x * blockDim.x + threadIdx.x;
    int row  = gtid >> 6;
    int lane = gtid & 63;
    if (row >= BATCH) return;
    const float* p = logits + (size_t)row * OUT_V;
    float a = p[lane], b = p[lane + 64];
    float m = fmaxf(a, b);
    #pragma unroll
    for (int o = 32; o > 0; o >>= 1) m = fmaxf(m, __shfl_xor(m, o));
    float s = expf(a - m) + expf(b - m);
    #pragma unroll
    for (int o = 32; o > 0; o >>= 1) s += __shfl_xor(s, o);
    if (lane == 0) {
        int t = tgt_row[row];
        if (t != 0) {                      // PAD mask
            float lse = m + logf(s);
            scores[row] += p[t] - lse;
        }
    }
}

// encoder_outputs[b, t, i] = enc_pad[t, i]  (broadcast over batch)
__global__ void bcast_enc_kernel(const float* __restrict__ enc_pad,
                                 float* __restrict__ out)
{
    int idx = blockIdx.x * blockDim.x + threadIdx.x;
    const int total = BATCH * MAXLEN * HID;
    if (idx >= total) return;
    int inner = idx % (MAXLEN * HID);
    out[idx] = enc_pad[inner];
}

// ---------------------------------------------------------------------------
extern "C" void kernel_launch(void* const* d_in, const int* in_sizes, int n_in,
                              void* d_out, int out_size, void* d_ws, size_t ws_size,
                              hipStream_t stream)
{
    const int*   input   = (const int*)  d_in[0];
    const float* enc_h0  = (const float*)d_in[1];
    const int*   target  = (const int*)  d_in[2];
    const float* enc_emb = (const float*)d_in[3];
    const float* enc_Wih = (const float*)d_in[4];
    const float* enc_Whh = (const float*)d_in[5];
    const float* enc_bih = (const float*)d_in[6];
    const float* enc_bhh = (const float*)d_in[7];
    const float* dec_emb = (const float*)d_in[8];
    const float* attn_W  = (const float*)d_in[9];
    const float* attn_b  = (const float*)d_in[10];
    const float* comb_W  = (const float*)d_in[11];
    const float* comb_b  = (const float*)d_in[12];
    const float* dec_Wih = (const float*)d_in[13];
    const float* dec_Whh = (const float*)d_in[14];
    const float* dec_bih = (const float*)d_in[15];
    const float* dec_bhh = (const float*)d_in[16];
    const float* out_W   = (const float*)d_in[17];
    const float* out_b   = (const float*)d_in[18];

    float* scores  = (float*)d_out;            // [BATCH]
    float* enc_out = scores + BATCH;           // [BATCH, MAXLEN, HID]

    // workspace layout (fp32), ~87 MB total
    float* ws = (float*)d_ws;
    float* h       = ws;  ws += BATCH * HID;
    float* emb     = ws;  ws += BATCH * HID;
    float* gi      = ws;  ws += BATCH * THID;
    float* gh      = ws;  ws += BATCH * THID;
    float* ctx     = ws;  ws += BATCH * HID;
    float* xbuf    = ws;  ws += BATCH * HID;
    float* logits  = ws;  ws += BATCH * OUT_V;
    float* attn    = ws;  ws += BATCH * MAXLEN;
    float* enc_pad = ws;  ws += MAXLEN * HID;

    const int ELEM_BLOCKS = (BATCH * HID + 255) / 256;               // 8192
    const int WAVEROW_BLOCKS = (BATCH * 64 + 255) / 256;             // 1024
    const dim3 g_gih(THID / BN, BATCH / BM);                         // 24 x 64
    const dim3 g_comb(HID / BN, BATCH / BM);                         //  8 x 64
    const dim3 g_attn(1, BATCH / BM);                                //  1 x 64
    const dim3 g_out((OUT_V + BN - 1) / BN, BATCH / BM);             //  2 x 64

    // scores = 0 ; h = encoder_hidden[0]
    hipMemsetAsync(scores, 0, BATCH * sizeof(float), stream);
    hipMemcpyAsync(h, enc_h0, (size_t)BATCH * HID * sizeof(float),
                   hipMemcpyDeviceToDevice, stream);

    // ---------------- encoder ----------------
    for (int t = 0; t < MAXLEN; ++t) {
        embed_kernel<<<ELEM_BLOCKS, 256, 0, stream>>>(input + (size_t)t * BATCH,
                                                      enc_emb, emb);
        gemm_nt<<<g_gih, 256, 0, stream>>>(emb, HID, enc_Wih, HID, enc_bih,
                                           gi, THID, BATCH, THID, HID, 0);
        gemm_nt<<<g_gih, 256, 0, stream>>>(h, HID, enc_Whh, HID, enc_bhh,
                                           gh, THID, BATCH, THID, HID, 0);
        gru_gates_kernel<<<ELEM_BLOCKS, 256, 0, stream>>>(gi, gh, h);
        copy_row0_kernel<<<2, 256, 0, stream>>>(h, enc_pad + (size_t)t * HID);
    }

    // encoder_outputs broadcast
    {
        int total = BATCH * MAXLEN * HID;
        bcast_enc_kernel<<<(total + 255) / 256, 256, 0, stream>>>(enc_pad, enc_out);
    }

    // ---------------- decoder ----------------
    for (int t = 0; t < MAXLEN; ++t) {
        const int* toks = (t == 0) ? (const int*)nullptr
                                   : target + (size_t)(t - 1) * BATCH;
        embed_kernel<<<ELEM_BLOCKS, 256, 0, stream>>>(toks, dec_emb, emb);

        // attention weights: softmax(emb @ Wa_e^T + h @ Wa_h^T + b)
        gemm_nt<<<g_attn, 256, 0, stream>>>(emb, HID, attn_W, 2 * HID, attn_b,
                                            attn, MAXLEN, BATCH, MAXLEN, HID, 0);
        gemm_nt<<<g_attn, 256, 0, stream>>>(h, HID, attn_W + HID, 2 * HID, nullptr,
                                            attn, MAXLEN, BATCH, MAXLEN, HID,
                                            FLAG_ACC);
        softmax41_kernel<<<WAVEROW_BLOCKS, 256, 0, stream>>>(attn);
        ctx_kernel<<<ELEM_BLOCKS, 256, 0, stream>>>(attn, enc_pad, ctx);

        // x = relu(emb @ Wc_e^T + ctx @ Wc_c^T + b)
        gemm_nt<<<g_comb, 256, 0, stream>>>(emb, HID, comb_W, 2 * HID, comb_b,
                                            xbuf, HID, BATCH, HID, HID, 0);
        gemm_nt<<<g_comb, 256, 0, stream>>>(ctx, HID, comb_W + HID, 2 * HID, nullptr,
                                            xbuf, HID, BATCH, HID, HID,
                                            FLAG_ACC | FLAG_RELU);

        // GRU cell
        gemm_nt<<<g_gih, 256, 0, stream>>>(xbuf, HID, dec_Wih, HID, dec_bih,
                                           gi, THID, BATCH, THID, HID, 0);
        gemm_nt<<<g_gih, 256, 0, stream>>>(h, HID, dec_Whh, HID, dec_bhh,
                                           gh, THID, BATCH, THID, HID, 0);
        gru_gates_kernel<<<ELEM_BLOCKS, 256, 0, stream>>>(gi, gh, h);

        // logits -> log_softmax -> gather
        gemm_nt<<<g_out, 256, 0, stream>>>(h, HID, out_W, HID, out_b,
                                           logits, OUT_V, BATCH, OUT_V, HID, 0);
        out_gather_kernel<<<WAVEROW_BLOCKS, 256, 0, stream>>>(
            logits, target + (size_t)t * BATCH, scores);
    }
}

// Round 2
// 9771.541 us; speedup vs baseline: 3.7344x; 3.7344x over previous
//
#include <hip/hip_runtime.h>
#include <math.h>

#define HID     512
#define THID    1536
#define OUT_V   128
#define MAXLEN  41
#define BATCH   4096
#define BOS_IDX 2

#define FLAG_RELU    1
#define FLAG_SOFTMAX 2

typedef __bf16 bf16x8 __attribute__((ext_vector_type(8)));
typedef float  f32x4  __attribute__((ext_vector_type(4)));

__device__ __forceinline__ unsigned bf16rne(float f) {
    unsigned u = __float_as_uint(f);
    return (u + 0x7fffu + ((u >> 16) & 1u)) >> 16;
}
__device__ __forceinline__ unsigned pack2(float lo, float hi) {
    return bf16rne(lo) | (bf16rne(hi) << 16);
}

// f32 -> bf16 (bit pattern in ushort), grid-stride
__global__ void cvt_bf16_kernel(const float* __restrict__ src,
                                unsigned short* __restrict__ dst, int n)
{
    int i = blockIdx.x * blockDim.x + threadIdx.x;
    int stride = gridDim.x * blockDim.x;
    for (; i < n; i += stride) dst[i] = (unsigned short)bf16rne(src[i]);
}

// ---------------------------------------------------------------------------
// MFMA bf16 GEMM:  C[M,N] = Acat[M,K] * B[N,K]^T + bias  (opt. relu/softmax)
//  A is fp32, split into two K-segments: A0 (rows optionally token-indexed)
//  for k < K0, A1 for k >= K0.  B is pre-converted bf16 (row-major [N,K]).
//  M must be a multiple of 128 (always 4096 here). K multiple of 64.
// ---------------------------------------------------------------------------
struct GemmDesc {
    const float* A0; const int* toks0; int lda0; int fixed0;
    const float* A1; int lda1;
    int K0; int K;
    const unsigned short* B; int ldb; int N;
    const float* bias;
    float* C; int ldc;
    int flags;
};

#define BM 128
#define BN 128
#define BK 64

__global__ __launch_bounds__(256)
void mgemm_kernel(GemmDesc dd0, GemmDesc dd1)
{
    const GemmDesc d = (blockIdx.z == 0) ? dd0 : dd1;

    __shared__ __align__(16) unsigned sA[BM * 32];   // 128 rows x 64 bf16, swizzled
    __shared__ __align__(16) unsigned sB[BN * 32];

    const int tid  = threadIdx.x;
    const int lane = tid & 63;
    const int wid  = tid >> 6;
    const int wr   = wid >> 1, wc = wid & 1;
    const int l15  = lane & 15, l4 = lane >> 4;
    const int bm   = blockIdx.y * BM;
    const int bn   = blockIdx.x * BN;

    const int sr      = tid >> 1;         // staging row 0..127
    const int sh      = (tid & 1) * 32;   // element offset within BK
    const int schunk0 = (tid & 1) * 4;    // first 16B chunk index

    f32x4 acc[4][4];
    #pragma unroll
    for (int m = 0; m < 4; ++m)
        #pragma unroll
        for (int n = 0; n < 4; ++n) {
            f32x4 z = {0.f, 0.f, 0.f, 0.f};
            acc[m][n] = z;
        }

    for (int k0 = 0; k0 < d.K; k0 += BK) {
        // ---- global loads to regs (A fp32, B bf16) ----
        float4 av[8];
        {
            int grow = bm + sr;
            const float* abase;
            int kloc;
            if (k0 < d.K0) {
                int r = d.toks0 ? d.toks0[grow]
                                : (d.fixed0 >= 0 ? d.fixed0 : grow);
                abase = d.A0 + (size_t)r * d.lda0;
                kloc  = k0;
            } else {
                abase = d.A1 + (size_t)grow * d.lda1;
                kloc  = k0 - d.K0;
            }
            const float4* ap = (const float4*)(abase + kloc + sh);
            #pragma unroll
            for (int i = 0; i < 8; ++i) av[i] = ap[i];
        }
        uint4 bw[4];
        {
            int brow = bn + sr;
            if (brow < d.N) {
                const uint4* bp = (const uint4*)(d.B + (size_t)brow * d.ldb + k0 + sh);
                #pragma unroll
                for (int i = 0; i < 4; ++i) bw[i] = bp[i];
            } else {
                #pragma unroll
                for (int i = 0; i < 4; ++i) bw[i] = make_uint4(0, 0, 0, 0);
            }
        }

        __syncthreads();   // previous iteration's LDS reads are done

        #pragma unroll
        for (int c = 0; c < 4; ++c) {
            uint4 w;
            w.x = pack2(av[2 * c].x,     av[2 * c].y);
            w.y = pack2(av[2 * c].z,     av[2 * c].w);
            w.z = pack2(av[2 * c + 1].x, av[2 * c + 1].y);
            w.w = pack2(av[2 * c + 1].z, av[2 * c + 1].w);
            int chunk = schunk0 + c;
            int swz   = (chunk ^ (sr & 7)) << 2;
            *(uint4*)&sA[sr * 32 + swz] = w;
            *(uint4*)&sB[sr * 32 + swz] = bw[c];
        }

        __syncthreads();

        // ---- 2 k-steps of 16 MFMAs ----
        #pragma unroll
        for (int ks = 0; ks < 2; ++ks) {
            bf16x8 af[4], bfr[4];
            #pragma unroll
            for (int m = 0; m < 4; ++m) {
                int row = wr * 64 + m * 16 + l15;
                int chunk = ks * 4 + l4;
                af[m] = *(const bf16x8*)&sA[row * 32 + ((chunk ^ (row & 7)) << 2)];
            }
            #pragma unroll
            for (int n = 0; n < 4; ++n) {
                int row = wc * 64 + n * 16 + l15;
                int chunk = ks * 4 + l4;
                bfr[n] = *(const bf16x8*)&sB[row * 32 + ((chunk ^ (row & 7)) << 2)];
            }
            #pragma unroll
            for (int m = 0; m < 4; ++m)
                #pragma unroll
                for (int n = 0; n < 4; ++n)
                    acc[m][n] = __builtin_amdgcn_mfma_f32_16x16x32_bf16(
                        af[m], bfr[n], acc[m][n], 0, 0, 0);
        }
    }

    // ---- epilogue ----
    if (d.flags & FLAG_SOFTMAX) {
        // N <= 48: all valid cols live in wave-col 0's fragments n=0..2
        if (wc == 0) {
            #pragma unroll
            for (int m = 0; m < 4; ++m) {
                #pragma unroll
                for (int j = 0; j < 4; ++j) {
                    float vv[3];
                    #pragma unroll
                    for (int n = 0; n < 3; ++n) {
                        int col = n * 16 + l15;
                        vv[n] = (col < d.N) ? (acc[m][n][j] + d.bias[col]) : -1e30f;
                    }
                    float mx = fmaxf(fmaxf(vv[0], vv[1]), vv[2]);
                    #pragma unroll
                    for (int o = 1; o < 16; o <<= 1) mx = fmaxf(mx, __shfl_xor(mx, o));
                    float s = 0.f;
                    #pragma unroll
                    for (int n = 0; n < 3; ++n) {
                        int col = n * 16 + l15;
                        float e = (col < d.N) ? expf(vv[n] - mx) : 0.f;
                        vv[n] = e; s += e;
                    }
                    #pragma unroll
                    for (int o = 1; o < 16; o <<= 1) s += __shfl_xor(s, o);
                    float inv = 1.f / s;
                    int row = bm + wr * 64 + m * 16 + l4 * 4 + j;
                    #pragma unroll
                    for (int n = 0; n < 3; ++n) {
                        int col = n * 16 + l15;
                        if (col < d.N)
                            d.C[(size_t)row * d.ldc + col] = vv[n] * inv;
                    }
                }
            }
        }
        return;
    }

    #pragma unroll
    for (int m = 0; m < 4; ++m) {
        #pragma unroll
        for (int n = 0; n < 4; ++n) {
            int col = bn + wc * 64 + n * 16 + l15;
            if (col >= d.N) continue;
            float bsv = d.bias ? d.bias[col] : 0.f;
            #pragma unroll
            for (int j = 0; j < 4; ++j) {
                int row = bm + wr * 64 + m * 16 + l4 * 4 + j;
                float v = acc[m][n][j] + bsv;
                if (d.flags & FLAG_RELU) v = fmaxf(v, 0.f);
                d.C[(size_t)row * d.ldc + col] = v;
            }
        }
    }
}

// ---------------------------------------------------------------------------
// GRU gates (r,z,n):  h = (1-z)*n + z*h ; optionally emit row 0 to enc_pad[t]
// ---------------------------------------------------------------------------
__global__ void gru_gates_kernel(const float* __restrict__ gi,
                                 const float* __restrict__ gh,
                                 float* __restrict__ h,
                                 float* __restrict__ row0_dst)
{
    int idx = blockIdx.x * blockDim.x + threadIdx.x;
    if (idx >= BATCH * HID) return;
    int b = idx / HID;
    int i = idx - b * HID;
    const float* gib = gi + (size_t)b * THID;
    const float* ghb = gh + (size_t)b * THID;
    float ir = gib[i], iz = gib[HID + i], in = gib[2 * HID + i];
    float hr = ghb[i], hz = ghb[HID + i], hn = ghb[2 * HID + i];
    float r = 1.f / (1.f + expf(-(ir + hr)));
    float z = 1.f / (1.f + expf(-(iz + hz)));
    float n = tanhf(in + r * hn);
    float hv = (1.f - z) * n + z * h[idx];
    h[idx] = hv;
    if (row0_dst && b == 0) row0_dst[i] = hv;
}

// ctx[b,i] = sum_t aw[b,t] * enc_pad[t,i]
__global__ void ctx_kernel(const float* __restrict__ aw,
                           const float* __restrict__ enc_pad,
                           float* __restrict__ ctx)
{
    int idx = blockIdx.x * blockDim.x + threadIdx.x;
    if (idx >= BATCH * HID) return;
    int b = idx / HID;
    int i = idx - b * HID;
    const float* awb = aw + (size_t)b * MAXLEN;
    float acc = 0.f;
    #pragma unroll
    for (int t = 0; t < MAXLEN; ++t)
        acc = fmaf(awb[t], enc_pad[t * HID + i], acc);
    ctx[idx] = acc;
}

// log_softmax over 128 logits + gather target + masked accumulate
__global__ void out_gather_kernel(const float* __restrict__ logits,
                                  const int* __restrict__ tgt_row,
                                  float* __restrict__ scores)
{
    int gtid = blockIdx.x * blockDim.x + threadIdx.x;
    int row  = gtid >> 6;
    int lane = gtid & 63;
    if (row >= BATCH) return;
    const float* p = logits + (size_t)row * OUT_V;
    float a = p[lane], b = p[lane + 64];
    float m = fmaxf(a, b);
    #pragma unroll
    for (int o = 32; o > 0; o >>= 1) m = fmaxf(m, __shfl_xor(m, o));
    float s = expf(a - m) + expf(b - m);
    #pragma unroll
    for (int o = 32; o > 0; o >>= 1) s += __shfl_xor(s, o);
    if (lane == 0) {
        int t = tgt_row[row];
        if (t != 0) {
            float lse = m + logf(s);
            scores[row] += p[t] - lse;
        }
    }
}

// encoder_outputs[b,t,i] = enc_pad[t,i]
__global__ void bcast_enc_kernel(const float* __restrict__ ep,
                                 float* __restrict__ out)
{
    const int inner4 = MAXLEN * HID / 4;                 // 5248
    const int total4 = BATCH * MAXLEN * HID / 4;
    const float4* e4 = (const float4*)ep;
    float4* o4 = (float4*)out;
    for (int i = blockIdx.x * blockDim.x + threadIdx.x; i < total4;
         i += gridDim.x * blockDim.x)
        o4[i] = e4[i % inner4];
}

// ---------------------------------------------------------------------------
extern "C" void kernel_launch(void* const* d_in, const int* in_sizes, int n_in,
                              void* d_out, int out_size, void* d_ws, size_t ws_size,
                              hipStream_t stream)
{
    const int*   input   = (const int*)  d_in[0];
    const float* enc_h0  = (const float*)d_in[1];
    const int*   target  = (const int*)  d_in[2];
    const float* enc_emb = (const float*)d_in[3];
    const float* enc_Wih = (const float*)d_in[4];
    const float* enc_Whh = (const float*)d_in[5];
    const float* enc_bih = (const float*)d_in[6];
    const float* enc_bhh = (const float*)d_in[7];
    const float* dec_emb = (const float*)d_in[8];
    const float* attn_W  = (const float*)d_in[9];
    const float* attn_b  = (const float*)d_in[10];
    const float* comb_W  = (const float*)d_in[11];
    const float* comb_b  = (const float*)d_in[12];
    const float* dec_Wih = (const float*)d_in[13];
    const float* dec_Whh = (const float*)d_in[14];
    const float* dec_bih = (const float*)d_in[15];
    const float* dec_bhh = (const float*)d_in[16];
    const float* out_W   = (const float*)d_in[17];
    const float* out_b   = (const float*)d_in[18];

    float* scores  = (float*)d_out;
    float* enc_out = scores + BATCH;

    // ---- workspace carve-up ----
    char* wp = (char*)d_ws;
    auto alloc = [&](size_t bytes) {
        void* r = (void*)wp;
        wp += (bytes + 255) & ~(size_t)255;
        return r;
    };
    unsigned short* b_eWih = (unsigned short*)alloc((size_t)THID * HID * 2);
    unsigned short* b_eWhh = (unsigned short*)alloc((size_t)THID * HID * 2);
    unsigned short* b_dWih = (unsigned short*)alloc((size_t)THID * HID * 2);
    unsigned short* b_dWhh = (unsigned short*)alloc((size_t)THID * HID * 2);
    unsigned short* b_comb = (unsigned short*)alloc((size_t)HID * 2 * HID * 2);
    unsigned short* b_attn = (unsigned short*)alloc((size_t)MAXLEN * 2 * HID * 2);
    unsigned short* b_outW = (unsigned short*)alloc((size_t)OUT_V * HID * 2);
    float* h       = (float*)alloc((size_t)BATCH * HID * 4);
    float* gi      = (float*)alloc((size_t)BATCH * THID * 4);
    float* gh      = (float*)alloc((size_t)BATCH * THID * 4);
    float* ctx     = (float*)alloc((size_t)BATCH * HID * 4);
    float* xbuf    = (float*)alloc((size_t)BATCH * HID * 4);
    float* logits  = (float*)alloc((size_t)BATCH * OUT_V * 4);
    float* attnbuf = (float*)alloc((size_t)BATCH * MAXLEN * 4);
    float* enc_pad = (float*)alloc((size_t)MAXLEN * HID * 4);

    // ---- weight conversion (once per launch) ----
    auto cvt = [&](const float* s, unsigned short* dx, int n) {
        int blocks = (n + 255) / 256; if (blocks > 1024) blocks = 1024;
        cvt_bf16_kernel<<<blocks, 256, 0, stream>>>(s, dx, n);
    };
    cvt(enc_Wih, b_eWih, THID * HID);
    cvt(enc_Whh, b_eWhh, THID * HID);
    cvt(dec_Wih, b_dWih, THID * HID);
    cvt(dec_Whh, b_dWhh, THID * HID);
    cvt(comb_W,  b_comb, HID * 2 * HID);
    cvt(attn_W,  b_attn, MAXLEN * 2 * HID);
    cvt(out_W,   b_outW, OUT_V * HID);

    hipMemsetAsync(scores, 0, BATCH * sizeof(float), stream);
    hipMemcpyAsync(h, enc_h0, (size_t)BATCH * HID * sizeof(float),
                   hipMemcpyDeviceToDevice, stream);

    const int ELEM_BLOCKS = (BATCH * HID) / 256;   // 8192
    const dim3 g_pair(THID / BN, BATCH / BM, 2);   // 12 x 32 x 2
    const dim3 g_attng(1, BATCH / BM, 1);
    const dim3 g_comb(HID / BN, BATCH / BM, 1);    // 4 x 32
    const dim3 g_outg(1, BATCH / BM, 1);

    // ---------------- encoder ----------------
    for (int t = 0; t < MAXLEN; ++t) {
        GemmDesc dgi = { enc_emb, input + (size_t)t * BATCH, HID, -1,
                         nullptr, 0, HID, HID,
                         b_eWih, HID, THID, enc_bih, gi, THID, 0 };
        GemmDesc dgh = { h, nullptr, HID, -1,
                         nullptr, 0, HID, HID,
                         b_eWhh, HID, THID, enc_bhh, gh, THID, 0 };
        mgemm_kernel<<<g_pair, 256, 0, stream>>>(dgi, dgh);
        gru_gates_kernel<<<ELEM_BLOCKS, 256, 0, stream>>>(
            gi, gh, h, enc_pad + (size_t)t * HID);
    }

    bcast_enc_kernel<<<4096, 256, 0, stream>>>(enc_pad, enc_out);

    // ---------------- decoder ----------------
    for (int t = 0; t < MAXLEN; ++t) {
        const int* toks = (t == 0) ? (const int*)nullptr
                                   : target + (size_t)(t - 1) * BATCH;
        int fixed = (t == 0) ? BOS_IDX : -1;

        GemmDesc da = { dec_emb, toks, HID, fixed,
                        h, HID, HID, 2 * HID,
                        b_attn, 2 * HID, MAXLEN, attn_b, attnbuf, MAXLEN,
                        FLAG_SOFTMAX };
        mgemm_kernel<<<g_attng, 256, 0, stream>>>(da, da);

        ctx_kernel<<<ELEM_BLOCKS, 256, 0, stream>>>(attnbuf, enc_pad, ctx);

        GemmDesc dc = { dec_emb, toks, HID, fixed,
                        ctx, HID, HID, 2 * HID,
                        b_comb, 2 * HID, HID, comb_b, xbuf, HID,
                        FLAG_RELU };
        mgemm_kernel<<<g_comb, 256, 0, stream>>>(dc, dc);

        GemmDesc dgi = { xbuf, nullptr, HID, -1,
                         nullptr, 0, HID, HID,
                         b_dWih, HID, THID, dec_bih, gi, THID, 0 };
        GemmDesc dgh = { h, nullptr, HID, -1,
                         nullptr, 0, HID, HID,
                         b_dWhh, HID, THID, dec_bhh, gh, THID, 0 };
        mgemm_kernel<<<g_pair, 256, 0, stream>>>(dgi, dgh);
        gru_gates_kernel<<<ELEM_BLOCKS, 256, 0, stream>>>(gi, gh, h, nullptr);

        GemmDesc dl = { h, nullptr, HID, -1,
                        nullptr, 0, HID, HID,
                        b_outW, HID, OUT_V, out_b, logits, OUT_V, 0 };
        mgemm_kernel<<<g_outg, 256, 0, stream>>>(dl, dl);

        out_gather_kernel<<<1024, 256, 0, stream>>>(
            logits, target + (size_t)t * BATCH, scores);
    }
}